// Round 9
// baseline (2352.335 us; speedup 1.0000x reference)
//
#include <hip/hip_runtime.h>
#include <hip/hip_bf16.h>

#define NN 100000
#define NE 400000
#define NG 1000

typedef __attribute__((ext_vector_type(8))) short bf16x8;
typedef __attribute__((ext_vector_type(4))) float f32x4;

// ---------------- bf16 <-> f32 helpers (bit-level, RNE) ----------------
__device__ __forceinline__ float bf2f(unsigned short h) {
    return __uint_as_float((unsigned)h << 16);
}
__device__ __forceinline__ unsigned short f2bf(float f) {
    unsigned u = __float_as_uint(f);
    return (unsigned short)((u + 0x7FFFu + ((u >> 16) & 1u)) >> 16);
}
__device__ __forceinline__ void up8(uint4 u, float v[8]) {
    v[0] = bf2f((unsigned short)u.x); v[1] = bf2f((unsigned short)(u.x >> 16));
    v[2] = bf2f((unsigned short)u.y); v[3] = bf2f((unsigned short)(u.y >> 16));
    v[4] = bf2f((unsigned short)u.z); v[5] = bf2f((unsigned short)(u.z >> 16));
    v[6] = bf2f((unsigned short)u.w); v[7] = bf2f((unsigned short)(u.w >> 16));
}
__device__ __forceinline__ uint4 pk8(const float v[8]) {
    uint4 r;
    r.x = (uint)f2bf(v[0]) | ((uint)f2bf(v[1]) << 16);
    r.y = (uint)f2bf(v[2]) | ((uint)f2bf(v[3]) << 16);
    r.z = (uint)f2bf(v[4]) | ((uint)f2bf(v[5]) << 16);
    r.w = (uint)f2bf(v[6]) | ((uint)f2bf(v[7]) << 16);
    return r;
}

// ---------------- diagnostic fallback ----------------
__global__ void diag_kernel(float* __restrict__ out, int n, float val) {
    int i = blockIdx.x * 256 + threadIdx.x;
    if (i < n) out[i] = val;
}

// ---------------- degree / invdeg ----------------
__global__ void deg_kernel(const int* __restrict__ dst, int* __restrict__ deg) {
    int e = blockIdx.x * 256 + threadIdx.x;
    if (e < NE) atomicAdd(&deg[dst[e]], 1);
}

__global__ void invdeg_kernel(const int* __restrict__ deg, float* __restrict__ invdeg) {
    int n = blockIdx.x * 256 + threadIdx.x;
    if (n < NN) invdeg[n] = 1.0f / (float)(deg[n] > 0 ? deg[n] : 1);
}

// ---------------- edge counting-sort by dst: scan + scatter ----------------
__global__ void scan1_kernel(const int* __restrict__ deg, int* __restrict__ off,
                             int* __restrict__ bsum) {
    __shared__ int s[1024];
    int tid = threadIdx.x;
    int i = blockIdx.x * 1024 + tid;
    int v = (i < NN) ? deg[i] : 0;
    s[tid] = v;
    __syncthreads();
    for (int d = 1; d < 1024; d <<= 1) {
        int add = (tid >= d) ? s[tid - d] : 0;
        __syncthreads();
        s[tid] += add;
        __syncthreads();
    }
    if (i < NN) off[i] = s[tid] - v;  // exclusive, block-local
    if (tid == 1023) bsum[blockIdx.x] = s[1023];
}

__global__ void scan2_kernel(int* __restrict__ bsum, int nb) {  // 1 block, 128 thr
    __shared__ int s[128];
    int tid = threadIdx.x;
    int v = (tid < nb) ? bsum[tid] : 0;
    s[tid] = v;
    __syncthreads();
    for (int d = 1; d < 128; d <<= 1) {
        int add = (tid >= d) ? s[tid - d] : 0;
        __syncthreads();
        s[tid] += add;
        __syncthreads();
    }
    if (tid < nb) bsum[tid] = s[tid] - v;  // exclusive block offsets
}

__global__ void scan3_kernel(int* __restrict__ off, const int* __restrict__ bsum,
                             int* __restrict__ cursor) {
    int i = blockIdx.x * 256 + threadIdx.x;
    if (i < NN) {
        int o = off[i] + bsum[i >> 10];
        off[i] = o;
        cursor[i] = o;
    }
    if (i == 0) off[NN] = NE;
}

__global__ void sortedge_kernel(const int* __restrict__ src, const int* __restrict__ dst,
                                int* __restrict__ cursor, int* __restrict__ ssrc,
                                int* __restrict__ sdst) {
    int e = blockIdx.x * 256 + threadIdx.x;
    if (e < NE) {
        int d = dst[e];
        int pos = atomicAdd(&cursor[d], 1);
        ssrc[pos] = src[e];
        sdst[pos] = d;
    }
}

// ---------------- conv1 node-level first linear (K=5), bf16 out ----------------
__global__ void conv1_node_kernel(const float* __restrict__ x, const float* __restrict__ W,
                                  unsigned short* __restrict__ RQ) {
    __shared__ float Ws[1280];  // [10][128]
    for (int i = threadIdx.x; i < 1280; i += 256) Ws[i] = W[i];
    __syncthreads();
    int c = threadIdx.x & 127;
    int which = threadIdx.x >> 7;
    for (int n = blockIdx.x; n < NN; n += gridDim.x) {
        float acc = 0.f;
        #pragma unroll
        for (int r = 0; r < 5; r++) {
            float xv = x[n * 5 + r];
            float bot = Ws[(5 + r) * 128 + c];
            float w = which ? bot : (Ws[r * 128 + c] - bot);
            acc = fmaf(xv, w, acc);
        }
        RQ[(size_t)n * 256 + threadIdx.x] = f2bf(acc);
    }
}

// ---------------- weight transpose+convert: Wt[N][K] bf16 from W[K][N] f32 ----------------
__global__ void wtrans_kernel(const float* __restrict__ W, unsigned short* __restrict__ Wt,
                              int K, int N) {
    int idx = blockIdx.x * 256 + threadIdx.x;
    if (idx >= K * N) return;
    int c = idx / K, k = idx - c * K;
    Wt[(size_t)c * K + k] = f2bf(W[(size_t)k * N + c]);
}

// ---------------- wprime transposed bf16: Wpt[2C][K] from W[2K][C] ----------------
__global__ void wprime_t_kernel(const float* __restrict__ W, unsigned short* __restrict__ Wpt,
                                int K, int C) {
    int idx = blockIdx.x * 256 + threadIdx.x;
    if (idx >= 2 * C * K) return;
    int n = idx / K, k = idx - n * K;
    float v;
    if (n < C) v = W[(size_t)k * C + n] - W[(size_t)(K + k) * C + n];
    else       v = W[(size_t)(K + k) * C + (n - C)];
    Wpt[(size_t)n * K + k] = f2bf(v);
}

// ---------------- per-node gather-stats: R[n] loop-invariant, Q gathered ----------------
template<int C>
__global__ void gstats_node_kernel(const unsigned short* __restrict__ RQ,
                                   const int* __restrict__ ssrc, const int* __restrict__ off,
                                   const float* __restrict__ bias,
                                   float* __restrict__ ssum, float* __restrict__ ssq) {
    constexpr int GPB = 256 / C;  // node groups per block
    const int t = threadIdx.x;
    const int c = t % C, g = t / C;
    float b = bias[c];
    float ls = 0.f, lq = 0.f;
    int chunk = (NN + gridDim.x - 1) / gridDim.x;
    int nb = blockIdx.x * chunk, ne = min(nb + chunk, NN);
    for (int n = nb + g; n < ne; n += GPB) {
        float R = bf2f(RQ[(size_t)n * (2 * C) + c]);
        int e0 = off[n], e1 = off[n + 1];
        for (int e = e0; e < e1; e++) {
            float v = R + bf2f(RQ[(size_t)ssrc[e] * (2 * C) + C + c]) + b;
            ls += v; lq += v * v;
        }
    }
    __shared__ float red[2][256];
    red[0][t] = ls; red[1][t] = lq;
    __syncthreads();
    if (t < C) {
        float s = 0.f, q = 0.f;
        #pragma unroll
        for (int gg = 0; gg < GPB; gg++) { s += red[0][gg * C + t]; q += red[1][gg * C + t]; }
        atomicAdd(&ssum[t], s);
        atomicAdd(&ssq[t], q);
    }
}

// ---------------- GraphNorm stats -> per-channel affine ----------------
__global__ void finalize_kernel(const float* __restrict__ ssum, const float* __restrict__ ssq,
                                const float* __restrict__ gn, int C, float invM,
                                float* __restrict__ alpha, float* __restrict__ beta) {
    int c = threadIdx.x;
    if (c >= C) return;
    float g = gn[c], b = gn[C + c], ms = gn[2 * C + c];
    float m = ssum[c] * invM;
    float var = ssq[c] * invM - m * m * ms * (2.f - ms);
    float inv = rsqrtf(var + 1e-5f);
    alpha[c] = g * inv;
    beta[c] = b - g * inv * ms * m;
}

// ================= MFMA GEMM v3 (round-8, unchanged): one-shot A staging =================
template<int TK, int BN, bool GATHER, bool NORMRELU, bool ROWSC, bool STATS, bool STORE,
         bool SCAT, bool AF32>
__global__ __launch_bounds__(256) void mgemm_kernel(
    const void* __restrict__ Av, const int* __restrict__ gsrc, const int* __restrict__ gdst,
    const float* __restrict__ biasIn, const unsigned short* __restrict__ Wt,
    const float* __restrict__ alpha, const float* __restrict__ beta,
    const float* __restrict__ rowscale, const float* __restrict__ biasOut,
    unsigned short* __restrict__ Cmat, int M, int N,
    float* __restrict__ ssum, float* __restrict__ ssq,
    const float* __restrict__ alphaO, const float* __restrict__ betaO,
    float* __restrict__ hsum) {
    constexpr int WNC = BN / 4;
    constexpr int NF = WNC / 16;
    constexpr int SPR = TK / 8;
    constexpr int ITER = 64 * SPR / 256;
    __shared__ __align__(16) unsigned short At[64][TK + 8];
    __shared__ __align__(16) float sAl[TK], sBe[TK], sBi[TK];
    __shared__ float sS[BN], sQ[BN];
    const int t = threadIdx.x;
    const int wave = t >> 6, lane = t & 63;
    const int l15 = lane & 15, lq = lane >> 4;
    const int r0 = blockIdx.y * 64;
    const int n0 = blockIdx.x * BN;

    if (NORMRELU) for (int i = t; i < TK; i += 256) { sAl[i] = alpha[i]; sBe[i] = beta[i]; }
    if (GATHER)   for (int i = t; i < TK; i += 256) { sBi[i] = biasIn[i]; }
    if (STATS && t < BN) { sS[t] = 0.f; sQ[t] = 0.f; }
    __syncthreads();

    const unsigned short* Abf = (const unsigned short*)Av;
    const float* Af = (const float*)Av;

    #pragma unroll
    for (int it = 0; it < ITER; it++) {
        int slot = it * 256 + t;
        int row = slot / SPR;
        int c0 = (slot - row * SPR) * 8;
        int ar = r0 + row;
        float v[8];
        if (GATHER) {
            int gd = gdst[ar], gs = gsrc[ar];
            uint4 pa4 = *(const uint4*)&Abf[(size_t)gd * (2 * TK) + c0];
            uint4 pq4 = *(const uint4*)&Abf[(size_t)gs * (2 * TK) + TK + c0];
            float pa[8], pq[8];
            up8(pa4, pa); up8(pq4, pq);
            #pragma unroll
            for (int i = 0; i < 8; i++) v[i] = pa[i] + pq[i] + sBi[c0 + i];
        } else if (AF32) {
            if (ar < M) {
                float4 f0 = *(const float4*)&Af[(size_t)ar * TK + c0];
                float4 f1 = *(const float4*)&Af[(size_t)ar * TK + c0 + 4];
                v[0] = f0.x; v[1] = f0.y; v[2] = f0.z; v[3] = f0.w;
                v[4] = f1.x; v[5] = f1.y; v[6] = f1.z; v[7] = f1.w;
            } else {
                #pragma unroll
                for (int i = 0; i < 8; i++) v[i] = 0.f;
            }
        } else {
            if (ar < M) {
                uint4 a4 = *(const uint4*)&Abf[(size_t)ar * TK + c0];
                up8(a4, v);
            } else {
                #pragma unroll
                for (int i = 0; i < 8; i++) v[i] = 0.f;
            }
        }
        if (NORMRELU) {
            #pragma unroll
            for (int i = 0; i < 8; i++)
                v[i] = fmaxf(fmaf(sAl[c0 + i], v[i], sBe[c0 + i]), 0.f);
        }
        if (ROWSC) {
            float rs = (ar < M) ? rowscale[ar] : 0.f;
            #pragma unroll
            for (int i = 0; i < 8; i++) v[i] *= rs;
        }
        *(uint4*)&At[row][c0] = pk8(v);
    }
    __syncthreads();

    const unsigned short* bp[NF];
    #pragma unroll
    for (int cf = 0; cf < NF; cf++)
        bp[cf] = &Wt[(size_t)(n0 + wave * WNC + 16 * cf + l15) * TK + lq * 8];

    f32x4 acc[4][NF];
    #pragma unroll
    for (int i = 0; i < 4; i++)
        #pragma unroll
        for (int j = 0; j < NF; j++) acc[i][j] = {0.f, 0.f, 0.f, 0.f};

    #pragma unroll
    for (int k0 = 0; k0 < TK; k0 += 32) {
        bf16x8 af[4];
        #pragma unroll
        for (int rf = 0; rf < 4; rf++)
            af[rf] = *(const bf16x8*)&At[16 * rf + l15][k0 + lq * 8];
        bf16x8 bfr[NF];
        #pragma unroll
        for (int cf = 0; cf < NF; cf++)
            bfr[cf] = *(const bf16x8*)(bp[cf] + k0);
        #pragma unroll
        for (int rf = 0; rf < 4; rf++)
            #pragma unroll
            for (int cf = 0; cf < NF; cf++)
                acc[rf][cf] = __builtin_amdgcn_mfma_f32_16x16x32_bf16(
                    af[rf], bfr[cf], acc[rf][cf], 0, 0, 0);
    }

    int cA[NF];
    float bO[NF], aO[NF], bOo[NF];
    #pragma unroll
    for (int cf = 0; cf < NF; cf++) {
        cA[cf] = n0 + wave * WNC + 16 * cf + l15;
        bO[cf] = (biasOut != nullptr) ? biasOut[cA[cf]] : 0.f;
        if (SCAT) { aO[cf] = alphaO[cA[cf]]; bOo[cf] = betaO[cA[cf]]; }
    }
    float ps[NF], pq[NF];
    #pragma unroll
    for (int cf = 0; cf < NF; cf++) { ps[cf] = 0.f; pq[cf] = 0.f; }
    #pragma unroll
    for (int rf = 0; rf < 4; rf++) {
        int rb = r0 + 16 * rf + lq * 4;
        int dd[4];
        if (SCAT) {
            #pragma unroll
            for (int jj = 0; jj < 4; jj++) dd[jj] = gdst[rb + jj];
        }
        #pragma unroll
        for (int cf = 0; cf < NF; cf++) {
            #pragma unroll
            for (int jj = 0; jj < 4; jj++) {
                float o = acc[rf][cf][jj] + bO[cf];
                if (STATS) { ps[cf] += o; pq[cf] += o * o; }
                if (STORE) {
                    int r = rb + jj;
                    if (r < M) Cmat[(size_t)r * N + cA[cf]] = f2bf(o);
                }
                if (SCAT) {
                    float h = fmaxf(fmaf(aO[cf], o, bOo[cf]), 0.f);
                    atomicAdd(&hsum[(size_t)dd[jj] * N + cA[cf]], h);
                }
            }
        }
    }
    if (STATS) {
        #pragma unroll
        for (int cf = 0; cf < NF; cf++) {
            float s = ps[cf], q = pq[cf];
            s += __shfl_xor(s, 16); s += __shfl_xor(s, 32);
            q += __shfl_xor(q, 16); q += __shfl_xor(q, 32);
            if (lq == 0) {
                atomicAdd(&sS[cA[cf] - n0], s);
                atomicAdd(&sQ[cA[cf] - n0], q);
            }
        }
        __syncthreads();
        if (t < BN) {
            atomicAdd(&ssum[n0 + t], sS[t]);
            atomicAdd(&ssq[n0 + t], sQ[t]);
        }
    }
}

// ---------------- per-node aggregate of sorted edge tensor Y: NO atomics ----------------
template<int C>
__global__ void aggregate_node_kernel(const unsigned short* __restrict__ Y,
                                      const int* __restrict__ off,
                                      const float* __restrict__ alpha,
                                      const float* __restrict__ beta,
                                      const float* __restrict__ invdeg,
                                      float* __restrict__ h) {
    constexpr int GPB = 256 / C;
    const int t = threadIdx.x;
    const int c = t % C, g = t / C;
    float al = alpha[c], be = beta[c];
    int chunk = (NN + gridDim.x - 1) / gridDim.x;
    int nb = blockIdx.x * chunk, ne = min(nb + chunk, NN);
    for (int n = nb + g; n < ne; n += GPB) {
        int e0 = off[n], e1 = off[n + 1];
        float s = 0.f;
        for (int e = e0; e < e1; e++)
            s += fmaxf(fmaf(al, bf2f(Y[(size_t)e * C + c]), be), 0.f);
        h[(size_t)n * C + c] = s * invdeg[n];
    }
}

// ---------------- conv3 per-node fused gather+norm+relu+mean: NO atomics ----------------
__global__ void aggregate_fg_node_kernel(const unsigned short* __restrict__ RQ,
                                         const int* __restrict__ ssrc,
                                         const int* __restrict__ off,
                                         const float* __restrict__ bias,
                                         const float* __restrict__ alpha,
                                         const float* __restrict__ beta,
                                         const float* __restrict__ invdeg,
                                         float* __restrict__ h) {
    int c = threadIdx.x;  // 256
    float b = bias[c], al = alpha[c], be = beta[c];
    int chunk = (NN + gridDim.x - 1) / gridDim.x;
    int nb = blockIdx.x * chunk, ne = min(nb + chunk, NN);
    for (int n = nb; n < ne; n++) {
        float R = bf2f(RQ[(size_t)n * 512 + c]);
        int e0 = off[n], e1 = off[n + 1];
        float s = 0.f;
        for (int e = e0; e < e1; e++) {
            float v = R + bf2f(RQ[(size_t)ssrc[e] * 512 + 256 + c]) + b;
            s += fmaxf(fmaf(al, v, be), 0.f);
        }
        h[(size_t)n * 256 + c] = s * invdeg[n];
    }
}

// ---------------- graph mean pool (h3 already node-mean) ----------------
__global__ void pool_kernel(const float* __restrict__ h3, const int* __restrict__ batch,
                            float* __restrict__ gsum, int* __restrict__ gcnt) {
    int chunk = (NN + gridDim.x - 1) / gridDim.x;
    int nbeg = blockIdx.x * chunk;
    int nend = min(nbeg + chunk, NN);
    if (nbeg >= nend) return;
    int t = threadIdx.x;  // 256 = channel
    int curg = batch[nbeg];
    float acc = 0.f;
    int cnt = 0;
    for (int n = nbeg; n < nend; n++) {
        int g = batch[n];
        if (g != curg) {
            atomicAdd(&gsum[(size_t)curg * 256 + t], acc);
            if (t == 0) atomicAdd(&gcnt[curg], cnt);
            curg = g; acc = 0.f; cnt = 0;
        }
        acc += h3[(size_t)n * 256 + t];
        cnt++;
    }
    atomicAdd(&gsum[(size_t)curg * 256 + t], acc);
    if (t == 0) atomicAdd(&gcnt[curg], cnt);
}

// ---------------- final graph MLP ----------------
__global__ void mlp_kernel(const float* __restrict__ gsum, const int* __restrict__ gcnt,
                           const float* __restrict__ W1, const float* __restrict__ b1,
                           const float* __restrict__ W2, const float* __restrict__ b2,
                           float* __restrict__ out) {
    int g = blockIdx.x;
    int t = threadIdx.x;  // 256
    __shared__ float grow[256];
    __shared__ float r0s[256], r1s[256];
    int cnt = gcnt[g];
    float inv = 1.0f / (float)(cnt > 0 ? cnt : 1);
    grow[t] = gsum[(size_t)g * 256 + t] * inv;
    __syncthreads();
    float acc = b1[t];
    for (int k = 0; k < 256; k++) acc = fmaf(grow[k], W1[k * 256 + t], acc);
    float h = fmaxf(acc, 0.f);
    r0s[t] = h * W2[t * 2 + 0];
    r1s[t] = h * W2[t * 2 + 1];
    __syncthreads();
    for (int s = 128; s > 0; s >>= 1) {
        if (t < s) { r0s[t] += r0s[t + s]; r1s[t] += r1s[t + s]; }
        __syncthreads();
    }
    if (t == 0) {
        out[g * 2 + 0] = r0s[0] + b2[0];
        out[g * 2 + 1] = r1s[0] + b2[1];
    }
}

extern "C" void kernel_launch(void* const* d_in, const int* in_sizes, int n_in,
                              void* d_out, int out_size, void* d_ws, size_t ws_size,
                              hipStream_t stream) {
    const float* x      = (const float*)d_in[0];
    const int*   ei     = (const int*)d_in[1];
    const int*   src0   = ei;
    const int*   dst0   = ei + NE;
    const int*   batch  = (const int*)d_in[2];
    const float* c1_w1  = (const float*)d_in[3];
    const float* c1_b1  = (const float*)d_in[4];
    const float* c1_gn1 = (const float*)d_in[5];
    const float* c1_w2  = (const float*)d_in[6];
    const float* c1_b2  = (const float*)d_in[7];
    const float* c1_gn2 = (const float*)d_in[8];
    const float* c1_w3  = (const float*)d_in[9];
    const float* c1_b3  = (const float*)d_in[10];
    const float* c1_gn3 = (const float*)d_in[11];
    const float* c2_w1  = (const float*)d_in[12];
    const float* c2_b1  = (const float*)d_in[13];
    const float* c2_gn1 = (const float*)d_in[14];
    const float* c2_w2  = (const float*)d_in[15];
    const float* c2_b2  = (const float*)d_in[16];
    const float* c2_gn2 = (const float*)d_in[17];
    const float* c3_w1  = (const float*)d_in[18];
    const float* c3_b1  = (const float*)d_in[19];
    const float* c3_gn1 = (const float*)d_in[20];
    const float* lin_w1 = (const float*)d_in[21];
    const float* lin_b1 = (const float*)d_in[22];
    const float* lin_w2 = (const float*)d_in[23];
    const float* lin_b2 = (const float*)d_in[24];
    float* out = (float*)d_out;

    // ======== workspace: ping-pong RA/RB (102.4 MB each) + ~8 MB tail ========
    //   RA: RQ1[NN,256]bf16 -> Y1c[NE,128]bf16 -> RQ2[NN,512]bf16 -> RQ3[NN,512]bf16
    //   RB: Y1b[NE,128]bf16 -> h1[NN,128]f32 -> h2sum[NN,256]f32 -> h3[NN,256]f32
    constexpr size_t REG_BYTES = (size_t)NE * 128 * 2;  // 102,400,000
    constexpr size_t NEED = 2 * REG_BYTES + 16 * 1024 * 1024;

    if (ws_size < NEED) {
        diag_kernel<<<(out_size + 255) / 256, 256, 0, stream>>>(
            out, out_size, (float)(ws_size >> 20));
        return;
    }

    char* base = (char*)d_ws;
    unsigned short* RA = (unsigned short*)base;
    unsigned short* RB = (unsigned short*)(base + REG_BYTES);
    float* h1    = (float*)RB;
    float* h2sum = (float*)RB;
    float* h3    = (float*)RB;
    char* p = base + 2 * REG_BYTES;
    auto alloc = [&](size_t bytes) -> void* {
        void* r = (void*)p;
        p += (bytes + 255) & ~(size_t)255;
        return r;
    };
    unsigned short* c1w2t = (unsigned short*)alloc((size_t)128 * 128 * 2);
    unsigned short* c1w3t = (unsigned short*)alloc((size_t)128 * 128 * 2);
    unsigned short* c2w2t = (unsigned short*)alloc((size_t)256 * 256 * 2);
    unsigned short* Wpt   = (unsigned short*)alloc((size_t)512 * 256 * 2);
    int*   deg    = (int*)alloc((size_t)NN * 4);
    float* invdeg = (float*)alloc((size_t)NN * 4);
    int*   off    = (int*)alloc((size_t)(NN + 1) * 4);
    int*   cursor = (int*)alloc((size_t)NN * 4);
    int*   bsum   = (int*)alloc((size_t)128 * 4);
    int*   ssrc   = (int*)alloc((size_t)NE * 4);
    int*   sdst   = (int*)alloc((size_t)NE * 4);
    float* ssum   = (float*)alloc(256 * 4);
    float* ssq    = (float*)alloc(256 * 4);
    float* al0    = (float*)alloc(256 * 4);
    float* be0    = (float*)alloc(256 * 4);
    float* al1    = (float*)alloc(256 * 4);
    float* be1    = (float*)alloc(256 * 4);
    float* gsum   = (float*)alloc((size_t)NG * 256 * 4);
    int*   gcnt   = (int*)alloc((size_t)NG * 4);

    const float invE = 1.0f / (float)NE;
    const int MT_E = NE / 64;
    const int MT_N = (NN + 63) / 64;
    const int NB = (NN + 1023) / 1024;  // 98 scan blocks

    hipMemsetAsync(deg, 0, (size_t)NN * 4, stream);
    hipMemsetAsync(gsum, 0, (size_t)NG * 256 * 4, stream);
    hipMemsetAsync(gcnt, 0, (size_t)NG * 4, stream);

    // ---- degree + counting sort of edges by dst ----
    deg_kernel<<<(NE + 255) / 256, 256, 0, stream>>>(dst0, deg);
    invdeg_kernel<<<(NN + 255) / 256, 256, 0, stream>>>(deg, invdeg);
    scan1_kernel<<<NB, 1024, 0, stream>>>(deg, off, bsum);
    scan2_kernel<<<1, 128, 0, stream>>>(bsum, NB);
    scan3_kernel<<<(NN + 255) / 256, 256, 0, stream>>>(off, bsum, cursor);
    sortedge_kernel<<<(NE + 255) / 256, 256, 0, stream>>>(src0, dst0, cursor, ssrc, sdst);

    wtrans_kernel<<<(128 * 128 + 255) / 256, 256, 0, stream>>>(c1_w2, c1w2t, 128, 128);
    wtrans_kernel<<<(128 * 128 + 255) / 256, 256, 0, stream>>>(c1_w3, c1w3t, 128, 128);
    wtrans_kernel<<<(256 * 256 + 255) / 256, 256, 0, stream>>>(c2_w2, c2w2t, 256, 256);

    // ================= conv1 =================
    conv1_node_kernel<<<2048, 256, 0, stream>>>(x, c1_w1, RA);
    hipMemsetAsync(ssum, 0, 256 * 4, stream);
    hipMemsetAsync(ssq, 0, 256 * 4, stream);
    gstats_node_kernel<128><<<2048, 256, 0, stream>>>(RA, ssrc, off, c1_b1, ssum, ssq);
    finalize_kernel<<<1, 256, 0, stream>>>(ssum, ssq, c1_gn1, 128, invE, al0, be0);

    hipMemsetAsync(ssum, 0, 256 * 4, stream);
    hipMemsetAsync(ssq, 0, 256 * 4, stream);
    mgemm_kernel<128, 128, true, true, false, true, true, false, false>
        <<<dim3(1, MT_E), 256, 0, stream>>>(RA, ssrc, sdst, c1_b1, c1w2t, al0, be0,
                                            nullptr, c1_b2, RB, NE, 128,
                                            ssum, ssq, nullptr, nullptr, nullptr);
    finalize_kernel<<<1, 256, 0, stream>>>(ssum, ssq, c1_gn2, 128, invE, al0, be0);

    hipMemsetAsync(ssum, 0, 256 * 4, stream);
    hipMemsetAsync(ssq, 0, 256 * 4, stream);
    mgemm_kernel<128, 128, false, true, false, true, true, false, false>
        <<<dim3(1, MT_E), 256, 0, stream>>>(RB, nullptr, nullptr, nullptr, c1w3t, al0, be0,
                                            nullptr, c1_b3, RA, NE, 128,
                                            ssum, ssq, nullptr, nullptr, nullptr);
    finalize_kernel<<<1, 256, 0, stream>>>(ssum, ssq, c1_gn3, 128, invE, al0, be0);

    // h1(RB) full overwrite per node — no memset, no atomics
    aggregate_node_kernel<128><<<2048, 256, 0, stream>>>(RA, off, al0, be0, invdeg, h1);

    // ================= conv2 =================
    wprime_t_kernel<<<(512 * 128 + 255) / 256, 256, 0, stream>>>(c2_w1, Wpt, 128, 256);
    mgemm_kernel<128, 256, false, false, false, false, true, false, true>
        <<<dim3(2, MT_N), 256, 0, stream>>>(h1, nullptr, nullptr, nullptr, Wpt,
                                            nullptr, nullptr, nullptr, nullptr, RA,
                                            NN, 512, nullptr, nullptr,
                                            nullptr, nullptr, nullptr);
    hipMemsetAsync(ssum, 0, 256 * 4, stream);
    hipMemsetAsync(ssq, 0, 256 * 4, stream);
    gstats_node_kernel<256><<<2048, 256, 0, stream>>>(RA, ssrc, off, c2_b1, ssum, ssq);
    finalize_kernel<<<1, 256, 0, stream>>>(ssum, ssq, c2_gn1, 256, invE, al0, be0);

    hipMemsetAsync(ssum, 0, 256 * 4, stream);
    hipMemsetAsync(ssq, 0, 256 * 4, stream);
    mgemm_kernel<256, 256, true, true, false, true, false, false, false>
        <<<dim3(1, MT_E), 256, 0, stream>>>(RA, ssrc, sdst, c2_b1, c2w2t, al0, be0,
                                            nullptr, c2_b2, nullptr, NE, 256,
                                            ssum, ssq, nullptr, nullptr, nullptr);
    finalize_kernel<<<1, 256, 0, stream>>>(ssum, ssq, c2_gn2, 256, invE, al1, be1);

    hipMemsetAsync(h2sum, 0, (size_t)NN * 256 * 4, stream);  // RB; h1 dead after node GEMM
    mgemm_kernel<256, 256, true, true, false, false, false, true, false>
        <<<dim3(1, MT_E), 256, 0, stream>>>(RA, ssrc, sdst, c2_b1, c2w2t, al0, be0,
                                            nullptr, c2_b2, nullptr, NE, 256,
                                            nullptr, nullptr, al1, be1, h2sum);

    // ================= conv3 =================
    wprime_t_kernel<<<(512 * 256 + 255) / 256, 256, 0, stream>>>(c3_w1, Wpt, 256, 256);
    mgemm_kernel<256, 256, false, false, true, false, true, false, true>
        <<<dim3(2, MT_N), 256, 0, stream>>>(h2sum, nullptr, nullptr, nullptr, Wpt,
                                            nullptr, nullptr, invdeg, nullptr, RA,
                                            NN, 512, nullptr, nullptr,
                                            nullptr, nullptr, nullptr);
    hipMemsetAsync(ssum, 0, 256 * 4, stream);
    hipMemsetAsync(ssq, 0, 256 * 4, stream);
    gstats_node_kernel<256><<<2048, 256, 0, stream>>>(RA, ssrc, off, c3_b1, ssum, ssq);
    finalize_kernel<<<1, 256, 0, stream>>>(ssum, ssq, c3_gn1, 256, invE, al0, be0);

    // h3(RB) full overwrite per node — no memset, no atomics
    aggregate_fg_node_kernel<<<2048, 256, 0, stream>>>(RA, ssrc, off, c3_b1, al0, be0,
                                                       invdeg, h3);

    // ================= pool + MLP =================
    pool_kernel<<<512, 256, 0, stream>>>(h3, batch, gsum, gcnt);
    mlp_kernel<<<NG, 256, 0, stream>>>(gsum, gcnt, lin_w1, lin_b1, lin_w2, lin_b2, out);
}

// Round 10
// 2063.861 us; speedup vs baseline: 1.1398x; 1.1398x over previous
//
#include <hip/hip_runtime.h>
#include <hip/hip_bf16.h>

#define NN 100000
#define NE 400000
#define NG 1000

typedef __attribute__((ext_vector_type(8))) short bf16x8;
typedef __attribute__((ext_vector_type(4))) float f32x4;

// ---------------- bf16 <-> f32 helpers (bit-level, RNE) ----------------
__device__ __forceinline__ float bf2f(unsigned short h) {
    return __uint_as_float((unsigned)h << 16);
}
__device__ __forceinline__ unsigned short f2bf(float f) {
    unsigned u = __float_as_uint(f);
    return (unsigned short)((u + 0x7FFFu + ((u >> 16) & 1u)) >> 16);
}
__device__ __forceinline__ void up8(uint4 u, float v[8]) {
    v[0] = bf2f((unsigned short)u.x); v[1] = bf2f((unsigned short)(u.x >> 16));
    v[2] = bf2f((unsigned short)u.y); v[3] = bf2f((unsigned short)(u.y >> 16));
    v[4] = bf2f((unsigned short)u.z); v[5] = bf2f((unsigned short)(u.z >> 16));
    v[6] = bf2f((unsigned short)u.w); v[7] = bf2f((unsigned short)(u.w >> 16));
}
__device__ __forceinline__ uint4 pk8(const float v[8]) {
    uint4 r;
    r.x = (uint)f2bf(v[0]) | ((uint)f2bf(v[1]) << 16);
    r.y = (uint)f2bf(v[2]) | ((uint)f2bf(v[3]) << 16);
    r.z = (uint)f2bf(v[4]) | ((uint)f2bf(v[5]) << 16);
    r.w = (uint)f2bf(v[6]) | ((uint)f2bf(v[7]) << 16);
    return r;
}
__device__ __forceinline__ void stout(float* p, float v) { *p = v; }
__device__ __forceinline__ void stout(unsigned short* p, float v) { *p = f2bf(v); }

// ---------------- diagnostic fallback ----------------
__global__ void diag_kernel(float* __restrict__ out, int n, float val) {
    int i = blockIdx.x * 256 + threadIdx.x;
    if (i < n) out[i] = val;
}

// ---------------- degree / invdeg ----------------
__global__ void deg_kernel(const int* __restrict__ dst, int* __restrict__ deg) {
    int e = blockIdx.x * 256 + threadIdx.x;
    if (e < NE) atomicAdd(&deg[dst[e]], 1);
}

__global__ void invdeg_kernel(const int* __restrict__ deg, float* __restrict__ invdeg) {
    int n = blockIdx.x * 256 + threadIdx.x;
    if (n < NN) invdeg[n] = 1.0f / (float)(deg[n] > 0 ? deg[n] : 1);
}

// ---------------- edge counting-sort by dst: scan + scatter ----------------
__global__ void scan1_kernel(const int* __restrict__ deg, int* __restrict__ off,
                             int* __restrict__ bsum) {
    __shared__ int s[1024];
    int tid = threadIdx.x;
    int i = blockIdx.x * 1024 + tid;
    int v = (i < NN) ? deg[i] : 0;
    s[tid] = v;
    __syncthreads();
    for (int d = 1; d < 1024; d <<= 1) {
        int add = (tid >= d) ? s[tid - d] : 0;
        __syncthreads();
        s[tid] += add;
        __syncthreads();
    }
    if (i < NN) off[i] = s[tid] - v;  // exclusive, block-local
    if (tid == 1023) bsum[blockIdx.x] = s[1023];
}

__global__ void scan2_kernel(int* __restrict__ bsum, int nb) {  // 1 block, 128 thr
    __shared__ int s[128];
    int tid = threadIdx.x;
    int v = (tid < nb) ? bsum[tid] : 0;
    s[tid] = v;
    __syncthreads();
    for (int d = 1; d < 128; d <<= 1) {
        int add = (tid >= d) ? s[tid - d] : 0;
        __syncthreads();
        s[tid] += add;
        __syncthreads();
    }
    if (tid < nb) bsum[tid] = s[tid] - v;  // exclusive block offsets
}

__global__ void scan3_kernel(int* __restrict__ off, const int* __restrict__ bsum,
                             int* __restrict__ cursor) {
    int i = blockIdx.x * 256 + threadIdx.x;
    if (i < NN) {
        int o = off[i] + bsum[i >> 10];
        off[i] = o;
        cursor[i] = o;
    }
    if (i == 0) off[NN] = NE;
}

__global__ void sortedge_kernel(const int* __restrict__ src, const int* __restrict__ dst,
                                int* __restrict__ cursor, int* __restrict__ ssrc,
                                int* __restrict__ sdst) {
    int e = blockIdx.x * 256 + threadIdx.x;
    if (e < NE) {
        int d = dst[e];
        int pos = atomicAdd(&cursor[d], 1);
        ssrc[pos] = src[e];
        sdst[pos] = d;
    }
}

// ---------------- conv1 node-level first linear (K=5), bf16 out ----------------
__global__ void conv1_node_kernel(const float* __restrict__ x, const float* __restrict__ W,
                                  unsigned short* __restrict__ RQ) {
    __shared__ float Ws[1280];  // [10][128]
    for (int i = threadIdx.x; i < 1280; i += 256) Ws[i] = W[i];
    __syncthreads();
    int c = threadIdx.x & 127;
    int which = threadIdx.x >> 7;
    for (int n = blockIdx.x; n < NN; n += gridDim.x) {
        float acc = 0.f;
        #pragma unroll
        for (int r = 0; r < 5; r++) {
            float xv = x[n * 5 + r];
            float bot = Ws[(5 + r) * 128 + c];
            float w = which ? bot : (Ws[r * 128 + c] - bot);
            acc = fmaf(xv, w, acc);
        }
        RQ[(size_t)n * 256 + threadIdx.x] = f2bf(acc);
    }
}

// ---------------- weight transpose+convert: Wt[N][K] bf16 from W[K][N] f32 ----------------
__global__ void wtrans_kernel(const float* __restrict__ W, unsigned short* __restrict__ Wt,
                              int K, int N) {
    int idx = blockIdx.x * 256 + threadIdx.x;
    if (idx >= K * N) return;
    int c = idx / K, k = idx - c * K;
    Wt[(size_t)c * K + k] = f2bf(W[(size_t)k * N + c]);
}

// ---------------- wprime transposed bf16: Wpt[2C][K] from W[2K][C] ----------------
__global__ void wprime_t_kernel(const float* __restrict__ W, unsigned short* __restrict__ Wpt,
                                int K, int C) {
    int idx = blockIdx.x * 256 + threadIdx.x;
    if (idx >= 2 * C * K) return;
    int n = idx / K, k = idx - n * K;
    float v;
    if (n < C) v = W[(size_t)k * C + n] - W[(size_t)(K + k) * C + n];
    else       v = W[(size_t)(K + k) * C + (n - C)];
    Wpt[(size_t)n * K + k] = f2bf(v);
}

// ---------------- per-node gather-stats: R[n] loop-invariant, Q gathered ----------------
template<int C>
__global__ void gstats_node_kernel(const unsigned short* __restrict__ RQ,
                                   const int* __restrict__ ssrc, const int* __restrict__ off,
                                   const float* __restrict__ bias,
                                   float* __restrict__ ssum, float* __restrict__ ssq) {
    constexpr int GPB = 256 / C;  // node groups per block
    const int t = threadIdx.x;
    const int c = t % C, g = t / C;
    float b = bias[c];
    float ls = 0.f, lq = 0.f;
    int chunk = (NN + gridDim.x - 1) / gridDim.x;
    int nb = blockIdx.x * chunk, ne = min(nb + chunk, NN);
    for (int n = nb + g; n < ne; n += GPB) {
        float R = bf2f(RQ[(size_t)n * (2 * C) + c]);
        int e0 = off[n], e1 = off[n + 1];
        for (int e = e0; e < e1; e++) {
            float v = R + bf2f(RQ[(size_t)ssrc[e] * (2 * C) + C + c]) + b;
            ls += v; lq += v * v;
        }
    }
    __shared__ float red[2][256];
    red[0][t] = ls; red[1][t] = lq;
    __syncthreads();
    if (t < C) {
        float s = 0.f, q = 0.f;
        #pragma unroll
        for (int gg = 0; gg < GPB; gg++) { s += red[0][gg * C + t]; q += red[1][gg * C + t]; }
        atomicAdd(&ssum[t], s);
        atomicAdd(&ssq[t], q);
    }
}

// ---------------- GraphNorm stats -> per-channel affine (stride/cnt split) ----------------
__global__ void finalize_kernel(const float* __restrict__ ssum, const float* __restrict__ ssq,
                                const float* __restrict__ gn, int stride, int cnt, float invM,
                                float* __restrict__ alpha, float* __restrict__ beta) {
    int c = threadIdx.x;
    if (c >= cnt) return;
    float g = gn[c], b = gn[stride + c], ms = gn[2 * stride + c];
    float m = ssum[c] * invM;
    float var = ssq[c] * invM - m * m * ms * (2.f - ms);
    float inv = rsqrtf(var + 1e-5f);
    alpha[c] = g * inv;
    beta[c] = b - g * inv * ms * m;
}

// ================= MFMA GEMM v3: one-shot A staging, barrier-free K-loop =================
template<int TK, int BN, bool GATHER, bool NORMRELU, bool ROWSC, bool STATS, bool STORE,
         bool SCAT, bool AF32>
__global__ __launch_bounds__(256) void mgemm_kernel(
    const void* __restrict__ Av, const int* __restrict__ gsrc, const int* __restrict__ gdst,
    const float* __restrict__ biasIn, const unsigned short* __restrict__ Wt,
    const float* __restrict__ alpha, const float* __restrict__ beta,
    const float* __restrict__ rowscale, const float* __restrict__ biasOut,
    unsigned short* __restrict__ Cmat, int M, int N,
    float* __restrict__ ssum, float* __restrict__ ssq,
    const float* __restrict__ alphaO, const float* __restrict__ betaO,
    float* __restrict__ hsum) {
    constexpr int WNC = BN / 4;
    constexpr int NF = WNC / 16;
    constexpr int SPR = TK / 8;
    constexpr int ITER = 64 * SPR / 256;
    __shared__ __align__(16) unsigned short At[64][TK + 8];
    __shared__ __align__(16) float sAl[TK], sBe[TK], sBi[TK];
    __shared__ float sS[BN], sQ[BN];
    const int t = threadIdx.x;
    const int wave = t >> 6, lane = t & 63;
    const int l15 = lane & 15, lq = lane >> 4;
    const int r0 = blockIdx.y * 64;
    const int n0 = blockIdx.x * BN;

    if (NORMRELU) for (int i = t; i < TK; i += 256) { sAl[i] = alpha[i]; sBe[i] = beta[i]; }
    if (GATHER)   for (int i = t; i < TK; i += 256) { sBi[i] = biasIn[i]; }
    if (STATS && t < BN) { sS[t] = 0.f; sQ[t] = 0.f; }
    __syncthreads();

    const unsigned short* Abf = (const unsigned short*)Av;
    const float* Af = (const float*)Av;

    #pragma unroll
    for (int it = 0; it < ITER; it++) {
        int slot = it * 256 + t;
        int row = slot / SPR;
        int c0 = (slot - row * SPR) * 8;
        int ar = r0 + row;
        float v[8];
        if (GATHER) {
            int gd = gdst[ar], gs = gsrc[ar];
            uint4 pa4 = *(const uint4*)&Abf[(size_t)gd * (2 * TK) + c0];
            uint4 pq4 = *(const uint4*)&Abf[(size_t)gs * (2 * TK) + TK + c0];
            float pa[8], pq[8];
            up8(pa4, pa); up8(pq4, pq);
            #pragma unroll
            for (int i = 0; i < 8; i++) v[i] = pa[i] + pq[i] + sBi[c0 + i];
        } else if (AF32) {
            if (ar < M) {
                float4 f0 = *(const float4*)&Af[(size_t)ar * TK + c0];
                float4 f1 = *(const float4*)&Af[(size_t)ar * TK + c0 + 4];
                v[0] = f0.x; v[1] = f0.y; v[2] = f0.z; v[3] = f0.w;
                v[4] = f1.x; v[5] = f1.y; v[6] = f1.z; v[7] = f1.w;
            } else {
                #pragma unroll
                for (int i = 0; i < 8; i++) v[i] = 0.f;
            }
        } else {
            if (ar < M) {
                uint4 a4 = *(const uint4*)&Abf[(size_t)ar * TK + c0];
                up8(a4, v);
            } else {
                #pragma unroll
                for (int i = 0; i < 8; i++) v[i] = 0.f;
            }
        }
        if (NORMRELU) {
            #pragma unroll
            for (int i = 0; i < 8; i++)
                v[i] = fmaxf(fmaf(sAl[c0 + i], v[i], sBe[c0 + i]), 0.f);
        }
        if (ROWSC) {
            float rs = (ar < M) ? rowscale[ar] : 0.f;
            #pragma unroll
            for (int i = 0; i < 8; i++) v[i] *= rs;
        }
        *(uint4*)&At[row][c0] = pk8(v);
    }
    __syncthreads();

    const unsigned short* bp[NF];
    #pragma unroll
    for (int cf = 0; cf < NF; cf++)
        bp[cf] = &Wt[(size_t)(n0 + wave * WNC + 16 * cf + l15) * TK + lq * 8];

    f32x4 acc[4][NF];
    #pragma unroll
    for (int i = 0; i < 4; i++)
        #pragma unroll
        for (int j = 0; j < NF; j++) acc[i][j] = {0.f, 0.f, 0.f, 0.f};

    #pragma unroll
    for (int k0 = 0; k0 < TK; k0 += 32) {
        bf16x8 af[4];
        #pragma unroll
        for (int rf = 0; rf < 4; rf++)
            af[rf] = *(const bf16x8*)&At[16 * rf + l15][k0 + lq * 8];
        bf16x8 bfr[NF];
        #pragma unroll
        for (int cf = 0; cf < NF; cf++)
            bfr[cf] = *(const bf16x8*)(bp[cf] + k0);
        #pragma unroll
        for (int rf = 0; rf < 4; rf++)
            #pragma unroll
            for (int cf = 0; cf < NF; cf++)
                acc[rf][cf] = __builtin_amdgcn_mfma_f32_16x16x32_bf16(
                    af[rf], bfr[cf], acc[rf][cf], 0, 0, 0);
    }

    int cA[NF];
    float bO[NF], aO[NF], bOo[NF];
    #pragma unroll
    for (int cf = 0; cf < NF; cf++) {
        cA[cf] = n0 + wave * WNC + 16 * cf + l15;
        bO[cf] = (biasOut != nullptr) ? biasOut[cA[cf]] : 0.f;
        if (SCAT) { aO[cf] = alphaO[cA[cf]]; bOo[cf] = betaO[cA[cf]]; }
    }
    float ps[NF], pq[NF];
    #pragma unroll
    for (int cf = 0; cf < NF; cf++) { ps[cf] = 0.f; pq[cf] = 0.f; }
    #pragma unroll
    for (int rf = 0; rf < 4; rf++) {
        int rb = r0 + 16 * rf + lq * 4;
        int dd[4];
        if (SCAT) {
            #pragma unroll
            for (int jj = 0; jj < 4; jj++) dd[jj] = gdst[rb + jj];
        }
        #pragma unroll
        for (int cf = 0; cf < NF; cf++) {
            #pragma unroll
            for (int jj = 0; jj < 4; jj++) {
                float o = acc[rf][cf][jj] + bO[cf];
                if (STATS) { ps[cf] += o; pq[cf] += o * o; }
                if (STORE) {
                    int r = rb + jj;
                    if (r < M) Cmat[(size_t)r * N + cA[cf]] = f2bf(o);
                }
                if (SCAT) {
                    float h = fmaxf(fmaf(aO[cf], o, bOo[cf]), 0.f);
                    atomicAdd(&hsum[(size_t)dd[jj] * N + cA[cf]], h);
                }
            }
        }
    }
    if (STATS) {
        #pragma unroll
        for (int cf = 0; cf < NF; cf++) {
            float s = ps[cf], q = pq[cf];
            s += __shfl_xor(s, 16); s += __shfl_xor(s, 32);
            q += __shfl_xor(q, 16); q += __shfl_xor(q, 32);
            if (lq == 0) {
                atomicAdd(&sS[cA[cf] - n0], s);
                atomicAdd(&sQ[cA[cf] - n0], q);
            }
        }
        __syncthreads();
        if (t < BN) {
            atomicAdd(&ssum[n0 + t], sS[t]);
            atomicAdd(&ssq[n0 + t], sQ[t]);
        }
    }
}

// ---------------- per-node aggregate of sorted edge tensor Y: NO atomics ----------------
// Writes h[n*ldH + coff + c] = invdeg[n] * sum_e relu(al*Y[e,c]+be); TOUT = f32 or bf16.
template<int C, typename TOUT>
__global__ void aggregate_node_kernel(const unsigned short* __restrict__ Y,
                                      const int* __restrict__ off,
                                      const float* __restrict__ alpha,
                                      const float* __restrict__ beta,
                                      const float* __restrict__ invdeg,
                                      TOUT* __restrict__ h, int ldH, int coff) {
    constexpr int GPB = 256 / C;
    const int t = threadIdx.x;
    const int c = t % C, g = t / C;
    float al = alpha[c], be = beta[c];
    int chunk = (NN + gridDim.x - 1) / gridDim.x;
    int nb = blockIdx.x * chunk, ne = min(nb + chunk, NN);
    for (int n = nb + g; n < ne; n += GPB) {
        int e0 = off[n], e1 = off[n + 1];
        float s = 0.f;
        for (int e = e0; e < e1; e++)
            s += fmaxf(fmaf(al, bf2f(Y[(size_t)e * C + c]), be), 0.f);
        stout(&h[(size_t)n * ldH + coff + c], s * invdeg[n]);
    }
}

// ---------------- conv3 per-node fused gather+norm+relu+mean: NO atomics ----------------
__global__ void aggregate_fg_node_kernel(const unsigned short* __restrict__ RQ,
                                         const int* __restrict__ ssrc,
                                         const int* __restrict__ off,
                                         const float* __restrict__ bias,
                                         const float* __restrict__ alpha,
                                         const float* __restrict__ beta,
                                         const float* __restrict__ invdeg,
                                         float* __restrict__ h) {
    int c = threadIdx.x;  // 256
    float b = bias[c], al = alpha[c], be = beta[c];
    int chunk = (NN + gridDim.x - 1) / gridDim.x;
    int nb = blockIdx.x * chunk, ne = min(nb + chunk, NN);
    for (int n = nb; n < ne; n++) {
        float R = bf2f(RQ[(size_t)n * 512 + c]);
        int e0 = off[n], e1 = off[n + 1];
        float s = 0.f;
        for (int e = e0; e < e1; e++) {
            float v = R + bf2f(RQ[(size_t)ssrc[e] * 512 + 256 + c]) + b;
            s += fmaxf(fmaf(al, v, be), 0.f);
        }
        h[(size_t)n * 256 + c] = s * invdeg[n];
    }
}

// ---------------- graph mean pool (h3 already node-mean) ----------------
__global__ void pool_kernel(const float* __restrict__ h3, const int* __restrict__ batch,
                            float* __restrict__ gsum, int* __restrict__ gcnt) {
    int chunk = (NN + gridDim.x - 1) / gridDim.x;
    int nbeg = blockIdx.x * chunk;
    int nend = min(nbeg + chunk, NN);
    if (nbeg >= nend) return;
    int t = threadIdx.x;  // 256 = channel
    int curg = batch[nbeg];
    if ((unsigned)curg >= NG) curg = 0;  // guard (profile-replay poison insurance)
    float acc = 0.f;
    int cnt = 0;
    for (int n = nbeg; n < nend; n++) {
        int g = batch[n];
        if ((unsigned)g >= NG) g = 0;
        if (g != curg) {
            atomicAdd(&gsum[(size_t)curg * 256 + t], acc);
            if (t == 0) atomicAdd(&gcnt[curg], cnt);
            curg = g; acc = 0.f; cnt = 0;
        }
        acc += h3[(size_t)n * 256 + t];
        cnt++;
    }
    atomicAdd(&gsum[(size_t)curg * 256 + t], acc);
    if (t == 0) atomicAdd(&gcnt[curg], cnt);
}

// ---------------- final graph MLP ----------------
__global__ void mlp_kernel(const float* __restrict__ gsum, const int* __restrict__ gcnt,
                           const float* __restrict__ W1, const float* __restrict__ b1,
                           const float* __restrict__ W2, const float* __restrict__ b2,
                           float* __restrict__ out) {
    int g = blockIdx.x;
    int t = threadIdx.x;  // 256
    __shared__ float grow[256];
    __shared__ float r0s[256], r1s[256];
    int cnt = gcnt[g];
    float inv = 1.0f / (float)(cnt > 0 ? cnt : 1);
    grow[t] = gsum[(size_t)g * 256 + t] * inv;
    __syncthreads();
    float acc = b1[t];
    for (int k = 0; k < 256; k++) acc = fmaf(grow[k], W1[k * 256 + t], acc);
    float h = fmaxf(acc, 0.f);
    r0s[t] = h * W2[t * 2 + 0];
    r1s[t] = h * W2[t * 2 + 1];
    __syncthreads();
    for (int s = 128; s > 0; s >>= 1) {
        if (t < s) { r0s[t] += r0s[t + s]; r1s[t] += r1s[t + s]; }
        __syncthreads();
    }
    if (t == 0) {
        out[g * 2 + 0] = r0s[0] + b2[0];
        out[g * 2 + 1] = r1s[0] + b2[1];
    }
}

extern "C" void kernel_launch(void* const* d_in, const int* in_sizes, int n_in,
                              void* d_out, int out_size, void* d_ws, size_t ws_size,
                              hipStream_t stream) {
    const float* x      = (const float*)d_in[0];
    const int*   ei     = (const int*)d_in[1];
    const int*   src0   = ei;
    const int*   dst0   = ei + NE;
    const int*   batch  = (const int*)d_in[2];
    const float* c1_w1  = (const float*)d_in[3];
    const float* c1_b1  = (const float*)d_in[4];
    const float* c1_gn1 = (const float*)d_in[5];
    const float* c1_w2  = (const float*)d_in[6];
    const float* c1_b2  = (const float*)d_in[7];
    const float* c1_gn2 = (const float*)d_in[8];
    const float* c1_w3  = (const float*)d_in[9];
    const float* c1_b3  = (const float*)d_in[10];
    const float* c1_gn3 = (const float*)d_in[11];
    const float* c2_w1  = (const float*)d_in[12];
    const float* c2_b1  = (const float*)d_in[13];
    const float* c2_gn1 = (const float*)d_in[14];
    const float* c2_w2  = (const float*)d_in[15];
    const float* c2_b2  = (const float*)d_in[16];
    const float* c2_gn2 = (const float*)d_in[17];
    const float* c3_w1  = (const float*)d_in[18];
    const float* c3_b1  = (const float*)d_in[19];
    const float* c3_gn1 = (const float*)d_in[20];
    const float* lin_w1 = (const float*)d_in[21];
    const float* lin_b1 = (const float*)d_in[22];
    const float* lin_w2 = (const float*)d_in[23];
    const float* lin_b2 = (const float*)d_in[24];
    float* out = (float*)d_out;

    // ======== workspace: RA/RB (102.4 MB each) + h2bf (51.2 MB) + ~7 MB tail ========
    //   RA: RQ1[NN,256]bf16 -> Y1c[NE,128]bf16 -> RQ2[NN,512]bf16 -> RQ3[NN,512]bf16
    //   RB: Y1b[NE,128]bf16 -> h1[NN,128]f32 -> Yh[NE,128]bf16 (x2 halves) -> h3[NN,256]f32
    //   h2bf[NN,256]bf16 in tail (conv2 output means; conv3 GEMM A-operand)
    constexpr size_t REG_BYTES = (size_t)NE * 128 * 2;   // 102,400,000
    constexpr size_t H2_BYTES  = (size_t)NN * 256 * 2;   // 51,200,000
    constexpr size_t NEED = 2 * REG_BYTES + H2_BYTES + 8 * 1024 * 1024;

    if (ws_size < NEED) {
        diag_kernel<<<(out_size + 255) / 256, 256, 0, stream>>>(
            out, out_size, (float)(ws_size >> 20));
        return;
    }

    char* base = (char*)d_ws;
    unsigned short* RA = (unsigned short*)base;
    unsigned short* RB = (unsigned short*)(base + REG_BYTES);
    float* h1 = (float*)RB;
    float* h3 = (float*)RB;
    char* p = base + 2 * REG_BYTES;
    auto alloc = [&](size_t bytes) -> void* {
        void* r = (void*)p;
        p += (bytes + 255) & ~(size_t)255;
        return r;
    };
    unsigned short* h2bf  = (unsigned short*)alloc(H2_BYTES);
    unsigned short* c1w2t = (unsigned short*)alloc((size_t)128 * 128 * 2);
    unsigned short* c1w3t = (unsigned short*)alloc((size_t)128 * 128 * 2);
    unsigned short* c2w2t = (unsigned short*)alloc((size_t)256 * 256 * 2);
    unsigned short* Wpt   = (unsigned short*)alloc((size_t)512 * 256 * 2);
    int*   deg    = (int*)alloc((size_t)NN * 4);
    float* invdeg = (float*)alloc((size_t)NN * 4);
    int*   off    = (int*)alloc((size_t)(NN + 1) * 4);
    int*   cursor = (int*)alloc((size_t)NN * 4);
    int*   bsum   = (int*)alloc((size_t)128 * 4);
    int*   ssrc   = (int*)alloc((size_t)NE * 4);
    int*   sdst   = (int*)alloc((size_t)NE * 4);
    float* ssum   = (float*)alloc(256 * 4);
    float* ssq    = (float*)alloc(256 * 4);
    float* al0    = (float*)alloc(256 * 4);
    float* be0    = (float*)alloc(256 * 4);
    float* al1    = (float*)alloc(256 * 4);
    float* be1    = (float*)alloc(256 * 4);
    float* gsum   = (float*)alloc((size_t)NG * 256 * 4);
    int*   gcnt   = (int*)alloc((size_t)NG * 4);

    const float invE = 1.0f / (float)NE;
    const int MT_E = NE / 64;
    const int MT_N = (NN + 63) / 64;
    const int NB = (NN + 1023) / 1024;  // 98 scan blocks

    hipMemsetAsync(deg, 0, (size_t)NN * 4, stream);
    hipMemsetAsync(gsum, 0, (size_t)NG * 256 * 4, stream);
    hipMemsetAsync(gcnt, 0, (size_t)NG * 4, stream);

    // ---- degree + counting sort of edges by dst ----
    deg_kernel<<<(NE + 255) / 256, 256, 0, stream>>>(dst0, deg);
    invdeg_kernel<<<(NN + 255) / 256, 256, 0, stream>>>(deg, invdeg);
    scan1_kernel<<<NB, 1024, 0, stream>>>(deg, off, bsum);
    scan2_kernel<<<1, 128, 0, stream>>>(bsum, NB);
    scan3_kernel<<<(NN + 255) / 256, 256, 0, stream>>>(off, bsum, cursor);
    sortedge_kernel<<<(NE + 255) / 256, 256, 0, stream>>>(src0, dst0, cursor, ssrc, sdst);

    wtrans_kernel<<<(128 * 128 + 255) / 256, 256, 0, stream>>>(c1_w2, c1w2t, 128, 128);
    wtrans_kernel<<<(128 * 128 + 255) / 256, 256, 0, stream>>>(c1_w3, c1w3t, 128, 128);
    wtrans_kernel<<<(256 * 256 + 255) / 256, 256, 0, stream>>>(c2_w2, c2w2t, 256, 256);

    // ================= conv1 =================
    conv1_node_kernel<<<2048, 256, 0, stream>>>(x, c1_w1, RA);
    hipMemsetAsync(ssum, 0, 256 * 4, stream);
    hipMemsetAsync(ssq, 0, 256 * 4, stream);
    gstats_node_kernel<128><<<2048, 256, 0, stream>>>(RA, ssrc, off, c1_b1, ssum, ssq);
    finalize_kernel<<<1, 256, 0, stream>>>(ssum, ssq, c1_gn1, 128, 128, invE, al0, be0);

    hipMemsetAsync(ssum, 0, 256 * 4, stream);
    hipMemsetAsync(ssq, 0, 256 * 4, stream);
    mgemm_kernel<128, 128, true, true, false, true, true, false, false>
        <<<dim3(1, MT_E), 256, 0, stream>>>(RA, ssrc, sdst, c1_b1, c1w2t, al0, be0,
                                            nullptr, c1_b2, RB, NE, 128,
                                            ssum, ssq, nullptr, nullptr, nullptr);
    finalize_kernel<<<1, 256, 0, stream>>>(ssum, ssq, c1_gn2, 128, 128, invE, al0, be0);

    hipMemsetAsync(ssum, 0, 256 * 4, stream);
    hipMemsetAsync(ssq, 0, 256 * 4, stream);
    mgemm_kernel<128, 128, false, true, false, true, true, false, false>
        <<<dim3(1, MT_E), 256, 0, stream>>>(RB, nullptr, nullptr, nullptr, c1w3t, al0, be0,
                                            nullptr, c1_b3, RA, NE, 128,
                                            ssum, ssq, nullptr, nullptr, nullptr);
    finalize_kernel<<<1, 256, 0, stream>>>(ssum, ssq, c1_gn3, 128, 128, invE, al0, be0);

    // h1(RB) per-node mean — no memset, no atomics
    aggregate_node_kernel<128, float><<<2048, 256, 0, stream>>>(RA, off, al0, be0, invdeg,
                                                                h1, 128, 0);

    // ================= conv2 =================
    wprime_t_kernel<<<(512 * 128 + 255) / 256, 256, 0, stream>>>(c2_w1, Wpt, 128, 256);
    // node GEMM: RQ2(RA) = h1(RB, already mean) @ Wp
    mgemm_kernel<128, 256, false, false, false, false, true, false, true>
        <<<dim3(2, MT_N), 256, 0, stream>>>(h1, nullptr, nullptr, nullptr, Wpt,
                                            nullptr, nullptr, nullptr, nullptr, RA,
                                            NN, 512, nullptr, nullptr,
                                            nullptr, nullptr, nullptr);
    hipMemsetAsync(ssum, 0, 256 * 4, stream);
    hipMemsetAsync(ssq, 0, 256 * 4, stream);
    gstats_node_kernel<256><<<2048, 256, 0, stream>>>(RA, ssrc, off, c2_b1, ssum, ssq);
    finalize_kernel<<<1, 256, 0, stream>>>(ssum, ssq, c2_gn1, 256, 256, invE, al0, be0);

    // L2 split-N: two half-GEMMs (N=128) with stats+store, then atomic-free aggregate.
    for (int half = 0; half < 2; half++) {
        int coff = half * 128;
        hipMemsetAsync(ssum, 0, 256 * 4, stream);
        hipMemsetAsync(ssq, 0, 256 * 4, stream);
        mgemm_kernel<256, 128, true, true, false, true, true, false, false>
            <<<dim3(1, MT_E), 256, 0, stream>>>(RA, ssrc, sdst, c2_b1,
                                                c2w2t + (size_t)coff * 256, al0, be0,
                                                nullptr, c2_b2 + coff, RB, NE, 128,
                                                ssum, ssq, nullptr, nullptr, nullptr);
        finalize_kernel<<<1, 256, 0, stream>>>(ssum, ssq, c2_gn2 + coff, 256, 128, invE,
                                               al1, be1);
        aggregate_node_kernel<128, unsigned short><<<2048, 256, 0, stream>>>(
            RB, off, al1, be1, invdeg, h2bf, 256, coff);
    }

    // ================= conv3 =================
    wprime_t_kernel<<<(512 * 256 + 255) / 256, 256, 0, stream>>>(c3_w1, Wpt, 256, 256);
    // node GEMM: RQ3(RA) = h2bf (bf16 means) @ Wp   [RQ2 dead after half-GEMMs]
    mgemm_kernel<256, 256, false, false, false, false, true, false, false>
        <<<dim3(2, MT_N), 256, 0, stream>>>(h2bf, nullptr, nullptr, nullptr, Wpt,
                                            nullptr, nullptr, nullptr, nullptr, RA,
                                            NN, 512, nullptr, nullptr,
                                            nullptr, nullptr, nullptr);
    hipMemsetAsync(ssum, 0, 256 * 4, stream);
    hipMemsetAsync(ssq, 0, 256 * 4, stream);
    gstats_node_kernel<256><<<2048, 256, 0, stream>>>(RA, ssrc, off, c3_b1, ssum, ssq);
    finalize_kernel<<<1, 256, 0, stream>>>(ssum, ssq, c3_gn1, 256, 256, invE, al0, be0);

    // h3(RB) per-node fused mean — no memset, no atomics   [Yh dead]
    aggregate_fg_node_kernel<<<2048, 256, 0, stream>>>(RA, ssrc, off, c3_b1, al0, be0,
                                                       invdeg, h3);

    // ================= pool + MLP =================
    pool_kernel<<<512, 256, 0, stream>>>(h3, batch, gsum, gcnt);
    mlp_kernel<<<NG, 256, 0, stream>>>(gsum, gcnt, lin_w1, lin_b1, lin_w2, lin_b2, out);
}